// Round 3
// baseline (252.128 us; speedup 1.0000x reference)
//
#include <hip/hip_runtime.h>
#include <hip/hip_cooperative_groups.h>

namespace cg = cooperative_groups;

#define HDIM 128
#define NPOS 1024
#define NCOL 512
#define LN_EPS 1e-3f
#define AS_STR 36
#define BS_STR 68

// ---------------------------------------------------------------------------
// Workspace (floats): AcT[128][1024], BcT[128][512], p[1024], v[1024],
// q[512], w[512], rowsum[1024], segsum[n_seq*512], segid[1024] (int)
// ---------------------------------------------------------------------------

union Smem {
    struct {
        float xs[4][HDIM];
        float ds[4][HDIM];
        float partm[8], partp[8], partv[8], mus[4];
    } p1;
    struct { float As[128 * AS_STR]; float Bs[128 * BS_STR]; } s;   // 53248 B
    struct { float comb[8 * 256]; float redr[512]; float redc[1024]; } r;
};

__device__ __forceinline__ int seg_of(int i, const int* __restrict__ lens, int n_seq) {
    int cum = 0;
    for (int s = 0; s < n_seq; ++s) {
        cum += lens[s];
        if (i < cum) return s;
    }
    return n_seq - 1;
}

// ===========================================================================
// Single cooperative kernel: 256 blocks x 512 threads.
//  Phase 1: per 4-row group, relu-GEMM -> @Wm-GEMM -> center -> AcT/BcT/p/v/q/w
//  Phase 2: 32x64 tile of dot(a_i,b_j) (K=128, k-split across wave halves),
//           exp epilogue, rowsum/segsum block-reduce + atomics
//  Phase 3: normalize own tile's e[] from registers -> out  (no E buffer)
// ===========================================================================
extern "C" __global__ void __launch_bounds__(512)
fused(const float* __restrict__ seq_feat, const float* __restrict__ col_feat,
      const float* __restrict__ Ws, const float* __restrict__ bsv,
      const float* __restrict__ Wc, const float* __restrict__ bcv,
      const float* __restrict__ Wm, const float* __restrict__ bmv,
      const float* __restrict__ gam, const float* __restrict__ Wo,
      const int* __restrict__ lens, int n_seq,
      float* __restrict__ AcT, float* __restrict__ BcT,
      float* __restrict__ p_arr, float* __restrict__ v_arr,
      float* __restrict__ q_arr, float* __restrict__ w_arr,
      float* __restrict__ rowsum, float* __restrict__ segsum,
      int* __restrict__ segid, float* __restrict__ out)
{
    __shared__ Smem sm;
    cg::grid_group grid = cg::this_grid();

    const int t    = threadIdx.x;
    const int b    = blockIdx.x;
    const int h    = t & 127;
    const int r    = t >> 7;
    const int wv   = t >> 6;
    const int lane = t & 63;

    // ---- housekeeping: zero accumulators + segid LUT ----
    {
        const int nsums = NPOS + n_seq * NCOL;
        int idx = b * 512 + t;
        if (idx < nsums) (idx < NPOS ? rowsum : segsum)[idx < NPOS ? idx : idx - NPOS] = 0.f;
        int idx2 = idx - nsums;
        if (idx2 >= 0 && idx2 < NPOS) segid[idx2] = seg_of(idx2, lens, n_seq);
    }

    // =================== Phase 1 ===================
    for (int g = b; g < (NPOS + NCOL) / 4; g += 256) {
        const bool  is_seq = (g < NPOS / 4);
        const int   i0 = (is_seq ? g : (g - NPOS / 4)) * 4;
        const float* X  = is_seq ? seq_feat : col_feat;
        const float* W1 = is_seq ? Ws : Wc;
        const float* b1 = is_seq ? bsv : bcv;

        if (t < 128) {
            int rr = t >> 5, k4 = (t & 31) * 4;
            *(float4*)&sm.p1.xs[rr][k4] = *(const float4*)&X[(i0 + rr) * HDIM + k4];
        }
        __syncthreads();

        // stage 1: d = relu(x_r . W1[:,h] + b1[h])
        float d;
        {
            float a0 = 0.f, a1 = 0.f, a2 = 0.f, a3 = 0.f;
            #pragma unroll 8
            for (int k = 0; k < HDIM; k += 4) {
                float4 x = *(const float4*)&sm.p1.xs[r][k];
                float w0 = W1[(k + 0) * HDIM + h];
                float w1 = W1[(k + 1) * HDIM + h];
                float w2 = W1[(k + 2) * HDIM + h];
                float w3 = W1[(k + 3) * HDIM + h];
                a0 += x.x * w0; a1 += x.y * w1; a2 += x.z * w2; a3 += x.w * w3;
            }
            d = fmaxf(b1[h] + ((a0 + a1) + (a2 + a3)), 0.f);
        }
        sm.p1.ds[r][h] = d;
        __syncthreads();

        // stage 2: aa = d_r . Wm[:,h] (+ bm on col side)
        float aa;
        {
            float a0 = 0.f, a1 = 0.f, a2 = 0.f, a3 = 0.f;
            #pragma unroll 8
            for (int k = 0; k < HDIM; k += 4) {
                float4 x = *(const float4*)&sm.p1.ds[r][k];
                float w0 = Wm[(k + 0) * HDIM + h];
                float w1 = Wm[(k + 1) * HDIM + h];
                float w2 = Wm[(k + 2) * HDIM + h];
                float w3 = Wm[(k + 3) * HDIM + h];
                a0 += x.x * w0; a1 += x.y * w1; a2 += x.z * w2; a3 += x.w * w3;
            }
            aa = (is_seq ? 0.f : bmv[h]) + ((a0 + a1) + (a2 + a3));
        }

        // row mean
        {
            float s = aa;
            #pragma unroll
            for (int off = 32; off; off >>= 1) s += __shfl_xor(s, off, 64);
            if (lane == 0) sm.p1.partm[wv] = s;
        }
        __syncthreads();
        if (t < 4) sm.p1.mus[t] = (sm.p1.partm[2 * t] + sm.p1.partm[2 * t + 1]) * (1.f / HDIM);
        __syncthreads();

        const float a  = aa - sm.p1.mus[r];
        const float gw = gam[h] * Wo[h];

        // p = dot(a, gamma*Wo), v = mean(a^2)
        {
            float sp = a * gw, sv = a * a;
            #pragma unroll
            for (int off = 32; off; off >>= 1) {
                sp += __shfl_xor(sp, off, 64);
                sv += __shfl_xor(sv, off, 64);
            }
            if (lane == 0) { sm.p1.partp[wv] = sp; sm.p1.partv[wv] = sv; }
        }
        sm.p1.xs[r][h] = a;   // transpose staging
        __syncthreads();
        if (t < 4) {
            (is_seq ? p_arr : q_arr)[i0 + t] = sm.p1.partp[2 * t] + sm.p1.partp[2 * t + 1];
            (is_seq ? v_arr : w_arr)[i0 + t] =
                (sm.p1.partv[2 * t] + sm.p1.partv[2 * t + 1]) * (1.f / HDIM);
        }
        if (t < 128) {
            float4 st = make_float4(sm.p1.xs[0][t], sm.p1.xs[1][t], sm.p1.xs[2][t], sm.p1.xs[3][t]);
            if (is_seq) *(float4*)&AcT[t * NPOS + i0] = st;
            else        *(float4*)&BcT[t * NCOL + i0] = st;
        }
        __syncthreads();
    }

    __threadfence();
    grid.sync();

    // =================== Phase 2 ===================
    const int tt = t & 255;
    const int tc = tt & 15;
    const int tr = tt >> 4;
    const int kbase = (t >> 8) * 64;
    const int i0 = (b & 31) * 32;
    const int j0 = (b >> 5) * 64;
    const int jj = j0 + 4 * tc;

    #pragma unroll
    for (int u = 0; u < 2; ++u) {
        int fid = t + 512 * u;
        int k = fid >> 3, m4 = fid & 7;
        *(float4*)&sm.s.As[k * AS_STR + 4 * m4] = *(const float4*)&AcT[k * NPOS + i0 + 4 * m4];
    }
    #pragma unroll
    for (int u = 0; u < 4; ++u) {
        int fid = t + 512 * u;
        int k = fid >> 4, n4 = fid & 15;
        *(float4*)&sm.s.Bs[k * BS_STR + 4 * n4] = *(const float4*)&BcT[k * NCOL + j0 + 4 * n4];
    }
    __syncthreads();

    float acc[8] = {0.f, 0.f, 0.f, 0.f, 0.f, 0.f, 0.f, 0.f};
    #pragma unroll 4
    for (int k = kbase; k < kbase + 64; ++k) {
        float2 a2 = *(const float2*)&sm.s.As[k * AS_STR + 2 * tr];
        float4 b4 = *(const float4*)&sm.s.Bs[k * BS_STR + 4 * tc];
        acc[0] += a2.x * b4.x; acc[1] += a2.x * b4.y; acc[2] += a2.x * b4.z; acc[3] += a2.x * b4.w;
        acc[4] += a2.y * b4.x; acc[5] += a2.y * b4.y; acc[6] += a2.y * b4.z; acc[7] += a2.y * b4.w;
    }

    const int seg_lo = segid[i0];
    const int seg_hi = segid[i0 + 31];
    __syncthreads();   // As/Bs dead; union reusable

    if (t >= 256) {
        #pragma unroll
        for (int j = 0; j < 8; ++j) sm.r.comb[j * 256 + tt] = acc[j];
    }
    __syncthreads();

    float e[2][4];
    if (t < 256) {
        #pragma unroll
        for (int j = 0; j < 8; ++j) acc[j] += sm.r.comb[j * 256 + tt];

        float4 q4 = *(const float4*)&q_arr[jj];
        float4 w4 = *(const float4*)&w_arr[jj];
        float rs[2];
        #pragma unroll
        for (int mm = 0; mm < 2; ++mm) {
            const int i = i0 + 2 * tr + mm;
            const float pi = p_arr[i];
            const float vi = v_arr[i];
            e[mm][0] = __expf((pi + q4.x) * rsqrtf(vi + w4.x + acc[4*mm+0] * (2.f/HDIM) + LN_EPS));
            e[mm][1] = __expf((pi + q4.y) * rsqrtf(vi + w4.y + acc[4*mm+1] * (2.f/HDIM) + LN_EPS));
            e[mm][2] = __expf((pi + q4.z) * rsqrtf(vi + w4.z + acc[4*mm+2] * (2.f/HDIM) + LN_EPS));
            e[mm][3] = __expf((pi + q4.w) * rsqrtf(vi + w4.w + acc[4*mm+3] * (2.f/HDIM) + LN_EPS));
            rs[mm] = e[mm][0] + e[mm][1] + e[mm][2] + e[mm][3];
        }
        sm.r.redr[(2 * tr + 0) * 16 + tc] = rs[0];
        sm.r.redr[(2 * tr + 1) * 16 + tc] = rs[1];
        #pragma unroll
        for (int u = 0; u < 4; ++u)
            sm.r.redc[(4 * tc + u) * 16 + tr] = e[0][u] + e[1][u];
    }
    __syncthreads();

    if (t < 32) {
        float s = 0.f;
        #pragma unroll
        for (int m = 0; m < 16; ++m) s += sm.r.redr[t * 16 + m];
        atomicAdd(&rowsum[i0 + t], s);
    } else if (t >= 32 && t < 96 && seg_lo == seg_hi) {
        int c = t - 32;
        float s = 0.f;
        #pragma unroll
        for (int m = 0; m < 16; ++m) s += sm.r.redc[c * 16 + m];
        atomicAdd(&segsum[seg_lo * NCOL + j0 + c], s);
    }
    if (seg_lo != seg_hi && t < 256) {
        // generic path: tile crosses a segment boundary (not hit for 8x128)
        #pragma unroll
        for (int mm = 0; mm < 2; ++mm) {
            const int i = i0 + 2 * tr + mm;
            const int sg = segid[i];
            #pragma unroll
            for (int u = 0; u < 4; ++u)
                atomicAdd(&segsum[sg * NCOL + jj + u], e[mm][u]);
        }
    }

    __threadfence();
    grid.sync();

    // =================== Phase 3: normalize own tile from registers ===================
    if (t < 256) {
        #pragma unroll
        for (int mm = 0; mm < 2; ++mm) {
            const int i = i0 + 2 * tr + mm;
            const float invr = 1.f / rowsum[i];
            const int sg = segid[i];
            float4 s4 = *(const float4*)&segsum[sg * NCOL + jj];
            float4 o;
            { float mc = e[mm][0] * invr, ms = e[mm][0] / s4.x; o.x = mc + ms - mc * ms; }
            { float mc = e[mm][1] * invr, ms = e[mm][1] / s4.y; o.y = mc + ms - mc * ms; }
            { float mc = e[mm][2] * invr, ms = e[mm][2] / s4.z; o.z = mc + ms - mc * ms; }
            { float mc = e[mm][3] * invr, ms = e[mm][3] / s4.w; o.w = mc + ms - mc * ms; }
            *(float4*)&out[i * NCOL + jj] = o;
        }
    }
}

// ===========================================================================
extern "C" void kernel_launch(void* const* d_in, const int* in_sizes, int n_in,
                              void* d_out, int out_size, void* d_ws, size_t ws_size,
                              hipStream_t stream) {
    const float* seq_feat = (const float*)d_in[0];
    const float* col_feat = (const float*)d_in[1];
    const int*   lens     = (const int*)d_in[2];
    const float* Ws   = (const float*)d_in[3];
    const float* bs   = (const float*)d_in[4];
    const float* Wc   = (const float*)d_in[5];
    const float* bc   = (const float*)d_in[6];
    const float* Wm   = (const float*)d_in[7];
    const float* bm   = (const float*)d_in[8];
    const float* gam  = (const float*)d_in[9];
    // d_in[10] = beta, d_in[12] = bo: provably cancel in both normalizations
    const float* Wo   = (const float*)d_in[11];
    float* out = (float*)d_out;
    int n_seq = in_sizes[2];

    float* ws     = (float*)d_ws;
    float* AcT    = ws;                    // 128*1024
    float* BcT    = AcT + HDIM * NPOS;     // 128*512
    float* p      = BcT + HDIM * NCOL;     // 1024
    float* v      = p + NPOS;              // 1024
    float* q      = v + NPOS;              // 512
    float* w      = q + NCOL;              // 512
    float* rowsum = w + NCOL;              // 1024
    float* segsum = rowsum + NPOS;         // n_seq*512
    int*   segid  = (int*)(segsum + n_seq * NCOL); // 1024 ints

    void* args[] = {
        (void*)&seq_feat, (void*)&col_feat, (void*)&Ws, (void*)&bs, (void*)&Wc, (void*)&bc,
        (void*)&Wm, (void*)&bm, (void*)&gam, (void*)&Wo, (void*)&lens, (void*)&n_seq,
        (void*)&AcT, (void*)&BcT, (void*)&p, (void*)&v, (void*)&q, (void*)&w,
        (void*)&rowsum, (void*)&segsum, (void*)&segid, (void*)&out
    };
    hipLaunchCooperativeKernel((void*)fused, dim3(256), dim3(512), args, 0, stream);
}

// Round 4
// 102.967 us; speedup vs baseline: 2.4486x; 2.4486x over previous
//
#include <hip/hip_runtime.h>

#define HDIM 128
#define NPOS 1024
#define NCOL 512
#define LN_EPS 1e-3f

// ---------------------------------------------------------------------------
// Workspace (floats): AcT[128][1024], BcT[128][512], p[1024], v[1024],
// q[512], w[512], rowsum[1024], segsum[n_seq*512], segid[1024] (int)
// ---------------------------------------------------------------------------

__device__ __forceinline__ int seg_of(int i, const int* __restrict__ lens, int n_seq) {
    int cum = 0;
    for (int s = 0; s < n_seq; ++s) {
        cum += lens[s];
        if (i < cum) return s;
    }
    return n_seq - 1;
}

// ===========================================================================
// k1: 384 blocks x 512 threads. Block b: 4 rows of seq (b<256) or col side.
// Thread (r = t>>7, h = t&127) computes one element of both GEMM stages.
// Shuffle reductions; LDS-transposed store of centered AcT/BcT (k-major).
// Also zeroes rowsum/segsum and fills segid LUT.
// ===========================================================================
extern "C" __global__ void __launch_bounds__(512)
k1_precompute(const float* __restrict__ seq_feat, const float* __restrict__ col_feat,
              const float* __restrict__ Ws, const float* __restrict__ bsv,
              const float* __restrict__ Wc, const float* __restrict__ bcv,
              const float* __restrict__ Wm, const float* __restrict__ bmv,
              const float* __restrict__ gam, const float* __restrict__ Wo,
              const int* __restrict__ lens, int n_seq,
              float* __restrict__ AcT, float* __restrict__ BcT,
              float* __restrict__ p_arr, float* __restrict__ v_arr,
              float* __restrict__ q_arr, float* __restrict__ w_arr,
              float* __restrict__ sums, int* __restrict__ segid)
{
    __shared__ float xs[4][HDIM];
    __shared__ float ds_[4][HDIM];
    __shared__ float partm[8], partp[8], partv[8], mus[4];

    const int t    = threadIdx.x;
    const int b    = blockIdx.x;
    const int h    = t & 127;
    const int r    = t >> 7;
    const int wv   = t >> 6;
    const int lane = t & 63;

    // housekeeping: zero accumulators + fill segid LUT
    {
        const int nsums = NPOS + n_seq * NCOL;
        int idx = b * 512 + t;
        if (idx < nsums) sums[idx] = 0.f;
        int idx2 = idx - nsums;
        if (idx2 >= 0 && idx2 < NPOS) segid[idx2] = seg_of(idx2, lens, n_seq);
    }

    const bool  is_seq = (b < NPOS / 4);
    const int   i0 = (is_seq ? b : (b - NPOS / 4)) * 4;
    const float* X  = is_seq ? seq_feat : col_feat;
    const float* W1 = is_seq ? Ws : Wc;
    const float* b1 = is_seq ? bsv : bcv;

    if (t < 128) {
        int rr = t >> 5, k4 = (t & 31) * 4;
        *(float4*)&xs[rr][k4] = *(const float4*)&X[(i0 + rr) * HDIM + k4];
    }
    __syncthreads();

    // stage 1: d = relu(x_r . W1[:,h] + b1[h])
    float d;
    {
        float a0 = 0.f, a1 = 0.f, a2 = 0.f, a3 = 0.f;
        #pragma unroll 8
        for (int k = 0; k < HDIM; k += 4) {
            float4 x = *(const float4*)&xs[r][k];
            float w0 = W1[(k + 0) * HDIM + h];
            float w1 = W1[(k + 1) * HDIM + h];
            float w2 = W1[(k + 2) * HDIM + h];
            float w3 = W1[(k + 3) * HDIM + h];
            a0 += x.x * w0; a1 += x.y * w1; a2 += x.z * w2; a3 += x.w * w3;
        }
        d = fmaxf(b1[h] + ((a0 + a1) + (a2 + a3)), 0.f);
    }
    ds_[r][h] = d;
    __syncthreads();

    // stage 2: aa = d_r . Wm[:,h] (+ bm on col side)
    float aa;
    {
        float a0 = 0.f, a1 = 0.f, a2 = 0.f, a3 = 0.f;
        #pragma unroll 8
        for (int k = 0; k < HDIM; k += 4) {
            float4 x = *(const float4*)&ds_[r][k];
            float w0 = Wm[(k + 0) * HDIM + h];
            float w1 = Wm[(k + 1) * HDIM + h];
            float w2 = Wm[(k + 2) * HDIM + h];
            float w3 = Wm[(k + 3) * HDIM + h];
            a0 += x.x * w0; a1 += x.y * w1; a2 += x.z * w2; a3 += x.w * w3;
        }
        aa = (is_seq ? 0.f : bmv[h]) + ((a0 + a1) + (a2 + a3));
    }

    // row mean
    {
        float s = aa;
        #pragma unroll
        for (int off = 32; off; off >>= 1) s += __shfl_xor(s, off, 64);
        if (lane == 0) partm[wv] = s;
    }
    __syncthreads();
    if (t < 4) mus[t] = (partm[2 * t] + partm[2 * t + 1]) * (1.f / HDIM);
    __syncthreads();

    const float a  = aa - mus[r];
    const float gw = gam[h] * Wo[h];

    // p = dot(a, gamma*Wo), v = mean(a^2)
    {
        float sp = a * gw, sv = a * a;
        #pragma unroll
        for (int off = 32; off; off >>= 1) {
            sp += __shfl_xor(sp, off, 64);
            sv += __shfl_xor(sv, off, 64);
        }
        if (lane == 0) { partp[wv] = sp; partv[wv] = sv; }
    }
    xs[r][h] = a;   // transpose staging
    __syncthreads();
    if (t < 4) {
        (is_seq ? p_arr : q_arr)[i0 + t] = partp[2 * t] + partp[2 * t + 1];
        (is_seq ? v_arr : w_arr)[i0 + t] = (partv[2 * t] + partv[2 * t + 1]) * (1.f / HDIM);
    }
    if (t < 128) {
        float4 st = make_float4(xs[0][t], xs[1][t], xs[2][t], xs[3][t]);
        if (is_seq) *(float4*)&AcT[t * NPOS + i0] = st;
        else        *(float4*)&BcT[t * NCOL + i0] = st;
    }
}

// ===========================================================================
// k2: 16x64 tile, 512 blocks x 512 threads (2 blocks/CU, 4 waves/SIMD).
// Waves 0-3 take k<64, waves 4-7 k>=64; combine through LDS.
// Thread (tr=row 0..15, tc=colgroup 0..15): 1x4 outputs.
// ===========================================================================
#define AS_STR 20
#define BS_STR 68

union K2Smem {
    struct { float As[128 * AS_STR]; float Bs[128 * BS_STR]; } s;   // 45 KB
    struct { float comb[256 * 4]; float redr[256]; float redc[1024]; } r;
};

extern "C" __global__ void __launch_bounds__(512)
k2_gemm(const float* __restrict__ AcT, const float* __restrict__ BcT,
        const float* __restrict__ p_arr, const float* __restrict__ v_arr,
        const float* __restrict__ q_arr, const float* __restrict__ w_arr,
        const int* __restrict__ segid, int n_seq,
        float* __restrict__ E, float* __restrict__ rowsum, float* __restrict__ segsum)
{
    __shared__ K2Smem sm;

    const int t  = threadIdx.x;
    const int tt = t & 255;
    const int tc = tt & 15;      // col group (4 cols)
    const int tr = tt >> 4;      // row 0..15
    const int kbase = (t >> 8) * 64;
    const int i0 = blockIdx.x * 16;
    const int j0 = blockIdx.y * 64;
    const int jj = j0 + 4 * tc;

    // stage A tile: 128k x 16m = 512 float4s (1 per thread)
    {
        int k = t >> 2, m4 = t & 3;
        *(float4*)&sm.s.As[k * AS_STR + 4 * m4] = *(const float4*)&AcT[k * NPOS + i0 + 4 * m4];
    }
    // stage B tile: 128k x 64n = 2048 float4s (4 per thread)
    #pragma unroll
    for (int u = 0; u < 4; ++u) {
        int fid = t + 512 * u;
        int k = fid >> 4, n4 = fid & 15;
        *(float4*)&sm.s.Bs[k * BS_STR + 4 * n4] = *(const float4*)&BcT[k * NCOL + j0 + 4 * n4];
    }
    __syncthreads();

    float acc[4] = {0.f, 0.f, 0.f, 0.f};
    #pragma unroll 8
    for (int k = kbase; k < kbase + 64; ++k) {
        float  a  = sm.s.As[k * AS_STR + tr];          // 16-lane broadcast: free
        float4 b4 = *(const float4*)&sm.s.Bs[k * BS_STR + 4 * tc];
        acc[0] += a * b4.x; acc[1] += a * b4.y; acc[2] += a * b4.z; acc[3] += a * b4.w;
    }

    const int seg_lo = segid[i0];
    const int seg_hi = segid[i0 + 15];
    __syncthreads();   // As/Bs dead; union reusable

    if (t >= 256) *(float4*)&sm.r.comb[tt * 4] = make_float4(acc[0], acc[1], acc[2], acc[3]);
    __syncthreads();

    float e[4];
    if (t < 256) {
        float4 c = *(const float4*)&sm.r.comb[tt * 4];
        acc[0] += c.x; acc[1] += c.y; acc[2] += c.z; acc[3] += c.w;

        const int i = i0 + tr;
        const float pi = p_arr[i];
        const float vi = v_arr[i];
        float4 q4 = *(const float4*)&q_arr[jj];
        float4 w4 = *(const float4*)&w_arr[jj];
        e[0] = __expf((pi + q4.x) * rsqrtf(vi + w4.x + acc[0] * (2.f/HDIM) + LN_EPS));
        e[1] = __expf((pi + q4.y) * rsqrtf(vi + w4.y + acc[1] * (2.f/HDIM) + LN_EPS));
        e[2] = __expf((pi + q4.z) * rsqrtf(vi + w4.z + acc[2] * (2.f/HDIM) + LN_EPS));
        e[3] = __expf((pi + q4.w) * rsqrtf(vi + w4.w + acc[3] * (2.f/HDIM) + LN_EPS));
        *(float4*)&E[i * NCOL + jj] = make_float4(e[0], e[1], e[2], e[3]);

        sm.r.redr[tr * 16 + tc] = e[0] + e[1] + e[2] + e[3];
        #pragma unroll
        for (int u = 0; u < 4; ++u)
            sm.r.redc[(4 * tc + u) * 16 + tr] = e[u];
    }
    __syncthreads();

    if (t < 16) {
        float s = 0.f;
        #pragma unroll
        for (int m = 0; m < 16; ++m) s += sm.r.redr[t * 16 + m];
        atomicAdd(&rowsum[i0 + t], s);
    } else if (t >= 16 && t < 80 && seg_lo == seg_hi) {
        int c = t - 16;
        float s = 0.f;
        #pragma unroll
        for (int m = 0; m < 16; ++m) s += sm.r.redc[c * 16 + m];
        atomicAdd(&segsum[seg_lo * NCOL + j0 + c], s);
    }
    if (seg_lo != seg_hi && t < 256) {
        // generic path: tile crosses a segment boundary (not hit for 8x128)
        const int sg = segid[i0 + tr];
        #pragma unroll
        for (int u = 0; u < 4; ++u)
            atomicAdd(&segsum[sg * NCOL + jj + u], e[u]);
    }
}

// ===========================================================================
// k3: out = M_c + M_s - M_c*M_s
// ===========================================================================
extern "C" __global__ void __launch_bounds__(256)
k3_final(const float* __restrict__ E, const float* __restrict__ rowsum,
         const float* __restrict__ segsum, const int* __restrict__ segid,
         float* __restrict__ out)
{
    const int gid = blockIdx.x * 256 + threadIdx.x;
    const int i = gid >> 7;
    const int j = (gid & 127) * 4;

    float4 e4 = *(const float4*)&E[i * NCOL + j];
    const float invr = 1.f / rowsum[i];
    const int sg = segid[i];
    float4 s4 = *(const float4*)&segsum[sg * NCOL + j];

    float4 o;
    { float mc = e4.x * invr, ms = e4.x / s4.x; o.x = mc + ms - mc * ms; }
    { float mc = e4.y * invr, ms = e4.y / s4.y; o.y = mc + ms - mc * ms; }
    { float mc = e4.z * invr, ms = e4.z / s4.z; o.z = mc + ms - mc * ms; }
    { float mc = e4.w * invr, ms = e4.w / s4.w; o.w = mc + ms - mc * ms; }
    *(float4*)&out[i * NCOL + j] = o;
}

// ===========================================================================
extern "C" void kernel_launch(void* const* d_in, const int* in_sizes, int n_in,
                              void* d_out, int out_size, void* d_ws, size_t ws_size,
                              hipStream_t stream) {
    const float* seq_feat = (const float*)d_in[0];
    const float* col_feat = (const float*)d_in[1];
    const int*   lens     = (const int*)d_in[2];
    const float* Ws   = (const float*)d_in[3];
    const float* bs   = (const float*)d_in[4];
    const float* Wc   = (const float*)d_in[5];
    const float* bc   = (const float*)d_in[6];
    const float* Wm   = (const float*)d_in[7];
    const float* bm   = (const float*)d_in[8];
    const float* gam  = (const float*)d_in[9];
    // d_in[10] = beta, d_in[12] = bo: provably cancel in both normalizations
    const float* Wo   = (const float*)d_in[11];
    float* out = (float*)d_out;
    const int n_seq = in_sizes[2];

    float* ws     = (float*)d_ws;
    float* AcT    = ws;                    // 128*1024
    float* BcT    = AcT + HDIM * NPOS;     // 128*512
    float* p      = BcT + HDIM * NCOL;     // 1024
    float* v      = p + NPOS;              // 1024
    float* q      = v + NPOS;              // 512
    float* w      = q + NCOL;              // 512
    float* sums   = w + NCOL;              // rowsum 1024 + segsum n_seq*512
    float* rowsum = sums;
    float* segsum = sums + NPOS;
    float* E      = segsum + n_seq * NCOL; // 1024*512
    int*   segid  = (int*)(E + NPOS * NCOL);

    hipLaunchKernelGGL(k1_precompute, dim3(NPOS / 4 + NCOL / 4), dim3(512), 0, stream,
                       seq_feat, col_feat, Ws, bs, Wc, bc, Wm, bm, gam, Wo,
                       lens, n_seq, AcT, BcT, p, v, q, w, sums, segid);
    hipLaunchKernelGGL(k2_gemm, dim3(NPOS / 16, NCOL / 64), dim3(512), 0, stream,
                       AcT, BcT, p, v, q, w, segid, n_seq, E, rowsum, segsum);
    hipLaunchKernelGGL(k3_final, dim3((NPOS * NCOL / 4) / 256), dim3(256), 0, stream,
                       E, rowsum, segsum, segid, out);
}